// Round 13
// baseline (1919.064 us; speedup 1.0000x reference)
//
#include <hip/hip_runtime.h>
#include <cstdint>
#include <cstddef>

// SNN_53618371723788: 2-layer SLSTM, B=65536, T=24, H=64, fp32.
// Pass 1: layer-1 recurrence -> spike bitmasks + final mem1 (d_ws).
// Pass 2: layer-2 recurrence (sparse ih) + extra step + fused Wout GEMV.
//
// R13: NB=16 batches/wave. Evidence: both passes sit at ~89% LDS-pipe
// utilization (ds_read_b128 ~12cyc/CU; each wave streams the full 128KB
// weight set per t for only 8 batches). Doubling batches/read halves LDS
// bytes/batch. Batch-halved (acc[8][4]) to fit the 88-reg 512-thr alloc.
// pass2 spk2 history: per-t ballot stored IN-PLACE over the consumed spk1
// slot (read-before-write in t), epilogue reloads (threadfence + vector
// loads + readlane) and replays the same fmaf chain -> frees 16 sb regs.

#define BB 65536
#define TT 24
#define NB 16  // batches per wave (two halves of 8)

__device__ __forceinline__ float bcastf(float v, int l) {
  return __int_as_float(__builtin_amdgcn_readlane(__float_as_int(v), l));
}
__device__ __forceinline__ float sigm(float v) {
  return __fdividef(1.0f, 1.0f + __expf(-v));
}
__device__ __forceinline__ float tanh_fast(float v) {
  return fmaf(-2.0f, __fdividef(1.0f, __expf(2.0f * v) + 1.0f), 1.0f);
}
__device__ __forceinline__ float wsum(float v) {
#pragma unroll
  for (int o = 32; o > 0; o >>= 1) v += __shfl_xor(v, o);
  return v;
}

__global__ __attribute__((amdgpu_waves_per_eu(2, 4))) __launch_bounds__(512)
void snn_pass1(
    const float* __restrict__ x, const float* __restrict__ Wih1,
    const float* __restrict__ Whh1, const float* __restrict__ bih1,
    const float* __restrict__ bhh1, const float* __restrict__ thr1p,
    unsigned long long* __restrict__ spk_out, float* __restrict__ mem1_out) {
  // P1[m][j].q = Whh1[q*64+j][m]
  __shared__ float4 P1[64][64];     // 64 KB
  __shared__ float stM[8][64][NB];  // 32 KB -> 96 KB total
  int tid = threadIdx.x;
  for (int idx = tid; idx < 16384; idx += 512) {
    int k = idx >> 6, m = idx & 63;
    ((float*)&P1[m][k & 63])[k >> 6] = Whh1[idx];
  }
  __syncthreads();
  int lane = tid & 63, wave = tid >> 6;
  int wb = (blockIdx.x * 8 + wave) * NB;  // first batch of this wave
  float thr1 = thr1p[0];
  float b1q[4], wq[4];
#pragma unroll
  for (int q = 0; q < 4; q++) {
    b1q[q] = bih1[q * 64 + lane] + bhh1[q * 64 + lane];
    wq[q] = Wih1[q * 64 + lane];
  }
  float syn[NB], mem[NB];
#pragma unroll
  for (int b = 0; b < NB; b++) { syn[b] = 0.0f; mem[b] = 0.0f; }

  for (int t = 0; t < TT; t++) {
#pragma unroll
    for (int b = 0; b < NB; b++) stM[wave][lane][b] = mem[b];
    unsigned long long myspk = 0;  // lane b keeps batch b's ballot
#pragma unroll
    for (int h = 0; h < 2; h++) {
      const int B0 = h * 8;
      float acc[8][4];
#pragma unroll
      for (int j = 0; j < 8; j++) {
        float xbt = x[(wb + B0 + j) * TT + t];  // lane-uniform -> s_load
#pragma unroll
        for (int q = 0; q < 4; q++) acc[j][q] = fmaf(xbt, wq[q], b1q[q]);
      }
#pragma unroll 8
      for (int m = 0; m < 64; m++) {
        float4 w = P1[m][lane];                         // per-lane b128
        float4 sa = *(const float4*)&stM[wave][m][B0];  // broadcast
        float4 sb4 = *(const float4*)&stM[wave][m][B0 + 4];
        float s[8] = {sa.x, sa.y, sa.z, sa.w, sb4.x, sb4.y, sb4.z, sb4.w};
#pragma unroll
        for (int j = 0; j < 8; j++) {
          acc[j][0] = fmaf(s[j], w.x, acc[j][0]);
          acc[j][1] = fmaf(s[j], w.y, acc[j][1]);
          acc[j][2] = fmaf(s[j], w.z, acc[j][2]);
          acc[j][3] = fmaf(s[j], w.w, acc[j][3]);
        }
      }
#pragma unroll
      for (int j = 0; j < 8; j++) {
        int b = B0 + j;
        float ig = sigm(acc[j][0]), fg = sigm(acc[j][1]);
        float gg = tanh_fast(acc[j][2]), og = sigm(acc[j][3]);
        float sn = fmaf(fg, syn[b], ig * gg);
        float rst = (mem[b] > thr1) ? thr1 : 0.0f;  // reset uses OLD mem
        float mn = fmaf(og, tanh_fast(sn), -rst);
        syn[b] = sn;
        mem[b] = mn;
        unsigned long long msk = __ballot(mn > thr1);  // wave-uniform
        if (lane == b) myspk = msk;
      }
      __builtin_amdgcn_sched_barrier(0);
    }
    if (lane < NB)
      spk_out[(size_t)t * BB + wb + lane] = myspk;
  }
#pragma unroll
  for (int b = 0; b < NB; b++)
    mem1_out[(size_t)(wb + b) * 64 + lane] = mem[b];
}

__global__ __attribute__((amdgpu_waves_per_eu(2, 4))) __launch_bounds__(512)
void snn_pass2(
    const float* __restrict__ Wih2, const float* __restrict__ Whh2,
    const float* __restrict__ bih2, const float* __restrict__ bhh2,
    const float* __restrict__ thr2p, const float* __restrict__ Wout,
    const float* __restrict__ bout,
    unsigned long long* __restrict__ spk_io,  // spk1 in, spk2 out (in-place)
    const float* __restrict__ mem1_in, float* __restrict__ out) {
  __shared__ float4 Pih[64][64];    // 64 KB
  __shared__ float4 Phh[64][64];    // 64 KB
  __shared__ float stM[8][64][NB];  // 32 KB -> 160 KB total
  int tid = threadIdx.x;
  for (int idx = tid; idx < 16384; idx += 512) {
    int k = idx >> 6, m = idx & 63;
    ((float*)&Pih[m][k & 63])[k >> 6] = Wih2[idx];
    ((float*)&Phh[m][k & 63])[k >> 6] = Whh2[idx];
  }
  __syncthreads();
  int lane = tid & 63, wave = tid >> 6;
  int wb = (blockIdx.x * 8 + wave) * NB;
  float thr2 = thr2p[0];
  float b2q[4];
#pragma unroll
  for (int q = 0; q < 4; q++) b2q[q] = bih2[q * 64 + lane] + bhh2[q * 64 + lane];
  float syn[NB], mem[NB];
#pragma unroll
  for (int b = 0; b < NB; b++) { syn[b] = 0.0f; mem[b] = 0.0f; }

  for (int t = 0; t < TT; t++) {
    // spk1 masks -> SGPR u64 (all 16 read BEFORE the in-place overwrite below)
    unsigned long long mk[NB];
#pragma unroll
    for (int b = 0; b < NB; b++) {
      unsigned long long v = spk_io[(size_t)t * BB + wb + b];
      unsigned lo = __builtin_amdgcn_readfirstlane((unsigned)v);
      unsigned hi = __builtin_amdgcn_readfirstlane((unsigned)(v >> 32));
      mk[b] = ((unsigned long long)hi << 32) | (unsigned long long)lo;
    }
#pragma unroll
    for (int b = 0; b < NB; b++) stM[wave][lane][b] = mem[b];
    unsigned long long myspk2 = 0;
#pragma unroll
    for (int h = 0; h < 2; h++) {
      const int B0 = h * 8;
      float acc[8][4];
#pragma unroll
      for (int j = 0; j < 8; j++) {
#pragma unroll
        for (int q = 0; q < 4; q++) acc[j][q] = b2q[q];
      }
      // dense hh half
#pragma unroll 4
      for (int m = 0; m < 64; m++) {
        float4 wh = Phh[m][lane];
        float4 sa = *(const float4*)&stM[wave][m][B0];
        float4 sb4 = *(const float4*)&stM[wave][m][B0 + 4];
        float s[8] = {sa.x, sa.y, sa.z, sa.w, sb4.x, sb4.y, sb4.z, sb4.w};
#pragma unroll
        for (int j = 0; j < 8; j++) {
          acc[j][0] = fmaf(s[j], wh.x, acc[j][0]);
          acc[j][1] = fmaf(s[j], wh.y, acc[j][1]);
          acc[j][2] = fmaf(s[j], wh.z, acc[j][2]);
          acc[j][3] = fmaf(s[j], wh.w, acc[j][3]);
        }
      }
      // sparse ih half: 4-deep pipeline, adds ascending-bit (order preserved)
#pragma unroll
      for (int j = 0; j < 8; j++) {
        int b = B0 + j;
        unsigned long long k = mk[b];
        while (__builtin_popcountll(k) >= 4) {
          int m0 = __builtin_ctzll(k); k &= k - 1;
          int m1 = __builtin_ctzll(k); k &= k - 1;
          int m2 = __builtin_ctzll(k); k &= k - 1;
          int m3 = __builtin_ctzll(k); k &= k - 1;
          float4 r0 = Pih[m0][lane];
          float4 r1 = Pih[m1][lane];
          float4 r2 = Pih[m2][lane];
          float4 r3 = Pih[m3][lane];
          acc[j][0] += r0.x; acc[j][1] += r0.y; acc[j][2] += r0.z; acc[j][3] += r0.w;
          acc[j][0] += r1.x; acc[j][1] += r1.y; acc[j][2] += r1.z; acc[j][3] += r1.w;
          acc[j][0] += r2.x; acc[j][1] += r2.y; acc[j][2] += r2.z; acc[j][3] += r2.w;
          acc[j][0] += r3.x; acc[j][1] += r3.y; acc[j][2] += r3.z; acc[j][3] += r3.w;
        }
        while (k) {
          int m0 = __builtin_ctzll(k); k &= k - 1;
          float4 r0 = Pih[m0][lane];
          acc[j][0] += r0.x; acc[j][1] += r0.y; acc[j][2] += r0.z; acc[j][3] += r0.w;
        }
        float ig = sigm(acc[j][0]), fg = sigm(acc[j][1]);
        float gg = tanh_fast(acc[j][2]), og = sigm(acc[j][3]);
        float sn = fmaf(fg, syn[b], ig * gg);
        float rst = (mem[b] > thr2) ? thr2 : 0.0f;
        float mn = fmaf(og, tanh_fast(sn), -rst);
        syn[b] = sn;
        mem[b] = mn;
        unsigned long long msk2 = __ballot(mn > thr2);  // wave-uniform
        if (lane == b) myspk2 = msk2;
      }
      __builtin_amdgcn_sched_barrier(0);
    }
    // overwrite the consumed spk1 slots with this t's spk2 ballots
    if (lane < NB)
      spk_io[(size_t)t * BB + wb + lane] = myspk2;
  }

  // extra step: input = final mem1 (dense), batch-halved, readlane broadcast.
  float mnx[NB];   // final mem2 per batch
  unsigned sfx = 0u;  // bit b = spk2_last of (batch b, neuron=lane)
#pragma unroll
  for (int h = 0; h < 2; h++) {
    const int B0 = h * 8;
    float m1[8];
#pragma unroll
    for (int j = 0; j < 8; j++) m1[j] = mem1_in[(size_t)(wb + B0 + j) * 64 + lane];
    float acc[8][4];
#pragma unroll
    for (int j = 0; j < 8; j++) {
#pragma unroll
      for (int q = 0; q < 4; q++) acc[j][q] = b2q[q];
    }
#pragma unroll 4
    for (int m = 0; m < 64; m++) {
      float4 wi = Pih[m][lane];
      float4 wh = Phh[m][lane];
#pragma unroll
      for (int j = 0; j < 8; j++) {
        float s1 = bcastf(m1[j], m);
        float s2 = bcastf(mem[B0 + j], m);
        acc[j][0] = fmaf(s1, wi.x, fmaf(s2, wh.x, acc[j][0]));
        acc[j][1] = fmaf(s1, wi.y, fmaf(s2, wh.y, acc[j][1]));
        acc[j][2] = fmaf(s1, wi.z, fmaf(s2, wh.z, acc[j][2]));
        acc[j][3] = fmaf(s1, wi.w, fmaf(s2, wh.w, acc[j][3]));
      }
    }
#pragma unroll
    for (int j = 0; j < 8; j++) {
      int b = B0 + j;
      float ig = sigm(acc[j][0]), fg = sigm(acc[j][1]);
      float gg = tanh_fast(acc[j][2]), og = sigm(acc[j][3]);
      float sn = fmaf(fg, syn[b], ig * gg);
      float rst = (mem[b] > thr2) ? thr2 : 0.0f;
      float mn = fmaf(og, tanh_fast(sn), -rst);
      mnx[b] = mn;
      sfx |= (mn > thr2) ? (1u << b) : 0u;
    }
    __builtin_amdgcn_sched_barrier(0);
  }

  // epilogue: reload spk2 ballots (own stores; fence for L1 visibility),
  // replay p0/p1 in the same fmaf order: t=0..23, then spk2_last, then mem2.
  __threadfence();
  float bo0 = bout[0], bo1 = bout[1];
  float vout = 0.0f;
#pragma unroll 2
  for (int b = 0; b < NB; b++) {
    unsigned long long mv = 0ull;
    if (lane < TT) mv = spk_io[(size_t)lane * BB + wb + b];  // lane = t (vector load)
    unsigned vlo = (unsigned)mv, vhi = (unsigned)(mv >> 32);
    float p0b = 0.0f, p1b = 0.0f;
#pragma unroll 4
    for (int t = 0; t < TT; t++) {
      unsigned lo = (unsigned)__builtin_amdgcn_readlane((int)vlo, t);
      unsigned hi = (unsigned)__builtin_amdgcn_readlane((int)vhi, t);
      unsigned long long mt = ((unsigned long long)hi << 32) | (unsigned long long)lo;
      float sf = ((mt >> lane) & 1ull) ? 1.0f : 0.0f;
      p0b = fmaf(sf, Wout[t * 64 + lane], p0b);
      p1b = fmaf(sf, Wout[1664 + t * 64 + lane], p1b);
    }
    float sfb = ((sfx >> b) & 1u) ? 1.0f : 0.0f;
    p0b = fmaf(sfb, Wout[1536 + lane], p0b);
    p1b = fmaf(sfb, Wout[1664 + 1536 + lane], p1b);
    p0b = fmaf(mnx[b], Wout[1600 + lane], p0b);
    p1b = fmaf(mnx[b], Wout[1664 + 1600 + lane], p1b);
    float r0 = wsum(p0b);
    float r1 = wsum(p1b);
    if (lane == 2 * b) vout = r0;
    if (lane == 2 * b + 1) vout = r1;
  }
  if (lane < 2 * NB)
    out[(size_t)wb * 2 + lane] = vout + ((lane & 1) ? bo1 : bo0);
}

extern "C" void kernel_launch(void* const* d_in, const int* in_sizes, int n_in,
                              void* d_out, int out_size, void* d_ws, size_t ws_size,
                              hipStream_t stream) {
  const float* x = (const float*)d_in[0];
  const float* Wih1 = (const float*)d_in[1];
  const float* Whh1 = (const float*)d_in[2];
  const float* bih1 = (const float*)d_in[3];
  const float* bhh1 = (const float*)d_in[4];
  const float* thr1 = (const float*)d_in[5];
  const float* Wih2 = (const float*)d_in[6];
  const float* Whh2 = (const float*)d_in[7];
  const float* bih2 = (const float*)d_in[8];
  const float* bhh2 = (const float*)d_in[9];
  const float* thr2 = (const float*)d_in[10];
  const float* Wout = (const float*)d_in[11];
  const float* bout = (const float*)d_in[12];

  unsigned long long* spk = (unsigned long long*)d_ws;
  float* mem1 = (float*)((char*)d_ws + (size_t)TT * BB * 8);

  const int grid = BB / (8 * NB);  // 512 blocks of 512 threads (8 waves x 16 b)
  snn_pass1<<<grid, 512, 0, stream>>>(x, Wih1, Whh1, bih1, bhh1, thr1, spk, mem1);
  snn_pass2<<<grid, 512, 0, stream>>>(Wih2, Whh2, bih2, bhh2, thr2, Wout, bout,
                                      spk, mem1, (float*)d_out);
}

// Round 14
// 1776.122 us; speedup vs baseline: 1.0805x; 1.0805x over previous
//
#include <hip/hip_runtime.h>
#include <cstdint>
#include <cstddef>

// SNN_53618371723788: 2-layer SLSTM, B=65536, T=24, H=64, fp32.
// Pass 1: layer-1 recurrence -> spike bitmasks + final mem1 (d_ws).
// Pass 2: layer-2 recurrence (sparse ih) + extra step + fused Wout GEMV.
//
// R14: v_pk_fma_f32 dense loops (config reverted to R12's best: NB=8,
// pass1 512thr / pass2 1024thr). Accumulators paired over adjacent batches:
// broadcast LDS float4 {s_b0..s_b3} already holds batch pairs in even-aligned
// VGPR pairs; weight splat via op_sel (no movs). 8 pk_fma/m/half replaces 16
// fma -> dense VALU stream halves. Per-half fma is IEEE-identical, same m
// order -> bit-exact. Sparse adds hit individual pair halves (scalar v_add).
// If this is neutral, pk fp32 is half-rate on gfx950 and we're at the fp32
// vector-pipe roofline.

#define BB 65536
#define TT 24
#define NB 8  // batch elements per wave (two halves of 4)

typedef float pf2 __attribute__((ext_vector_type(2)));

// acc.lo += s.lo * w.lo ; acc.hi += s.hi * w.lo   (w splat = LOW half)
__device__ __forceinline__ void pk_fma_wlo(pf2& acc, pf2 s, pf2 w) {
  asm("v_pk_fma_f32 %0, %1, %2, %0 op_sel:[0,0,0] op_sel_hi:[1,0,1]"
      : "+v"(acc) : "v"(s), "v"(w));
}
// acc.lo += s.lo * w.hi ; acc.hi += s.hi * w.hi   (w splat = HIGH half)
__device__ __forceinline__ void pk_fma_whi(pf2& acc, pf2 s, pf2 w) {
  asm("v_pk_fma_f32 %0, %1, %2, %0 op_sel:[0,1,0] op_sel_hi:[1,1,1]"
      : "+v"(acc) : "v"(s), "v"(w));
}

__device__ __forceinline__ float bcastf(float v, int l) {
  return __int_as_float(__builtin_amdgcn_readlane(__float_as_int(v), l));
}
__device__ __forceinline__ float sigm(float v) {
  return __fdividef(1.0f, 1.0f + __expf(-v));
}
__device__ __forceinline__ float tanh_fast(float v) {
  return fmaf(-2.0f, __fdividef(1.0f, __expf(2.0f * v) + 1.0f), 1.0f);
}
__device__ __forceinline__ float wsum(float v) {
#pragma unroll
  for (int o = 32; o > 0; o >>= 1) v += __shfl_xor(v, o);
  return v;
}

__global__ __attribute__((amdgpu_waves_per_eu(4, 4))) __launch_bounds__(512)
void snn_pass1(
    const float* __restrict__ x, const float* __restrict__ Wih1,
    const float* __restrict__ Whh1, const float* __restrict__ bih1,
    const float* __restrict__ bhh1, const float* __restrict__ thr1p,
    unsigned long long* __restrict__ spk_out, float* __restrict__ mem1_out) {
  // P1[m][j].q = Whh1[q*64+j][m]
  __shared__ float4 P1[64][64];     // 64 KB
  __shared__ float stM[8][64][NB];  // 16 KB
  int tid = threadIdx.x;
  for (int idx = tid; idx < 16384; idx += 512) {
    int k = idx >> 6, m = idx & 63;
    ((float*)&P1[m][k & 63])[k >> 6] = Whh1[idx];
  }
  __syncthreads();
  int lane = tid & 63, wave = tid >> 6;
  int wb = (blockIdx.x * 8 + wave) * NB;  // first batch of this wave
  float thr1 = thr1p[0];
  float b1q[4], wq[4];
#pragma unroll
  for (int q = 0; q < 4; q++) {
    b1q[q] = bih1[q * 64 + lane] + bhh1[q * 64 + lane];
    wq[q] = Wih1[q * 64 + lane];
  }
  float syn[NB], mem[NB];
#pragma unroll
  for (int b = 0; b < NB; b++) { syn[b] = 0.0f; mem[b] = 0.0f; }

  for (int t = 0; t < TT; t++) {
#pragma unroll
    for (int b = 0; b < NB; b++) stM[wave][lane][b] = mem[b];
    unsigned long long myspk = 0;  // lane b keeps batch b's ballot
#pragma unroll
    for (int h = 0; h < 2; h++) {
      const int B0 = h * 4;
      // a2[q][p] = {acc(batch B0+2p, gate q), acc(batch B0+2p+1, gate q)}
      pf2 a2[4][2];
#pragma unroll
      for (int p = 0; p < 2; p++) {
        float x0 = x[(wb + B0 + 2 * p) * TT + t];
        float x1 = x[(wb + B0 + 2 * p + 1) * TT + t];
#pragma unroll
        for (int q = 0; q < 4; q++)
          a2[q][p] = (pf2){fmaf(x0, wq[q], b1q[q]), fmaf(x1, wq[q], b1q[q])};
      }
#pragma unroll 8
      for (int m = 0; m < 64; m++) {
        float4 w = P1[m][lane];                          // per-lane b128
        float4 sa = *(const float4*)&stM[wave][m][B0];   // broadcast pairs
        pf2 s01 = {sa.x, sa.y}, s23 = {sa.z, sa.w};
        pf2 wxy = {w.x, w.y}, wzw = {w.z, w.w};
        pk_fma_wlo(a2[0][0], s01, wxy);  // q0 <- w.x
        pk_fma_whi(a2[1][0], s01, wxy);  // q1 <- w.y
        pk_fma_wlo(a2[2][0], s01, wzw);  // q2 <- w.z
        pk_fma_whi(a2[3][0], s01, wzw);  // q3 <- w.w
        pk_fma_wlo(a2[0][1], s23, wxy);
        pk_fma_whi(a2[1][1], s23, wxy);
        pk_fma_wlo(a2[2][1], s23, wzw);
        pk_fma_whi(a2[3][1], s23, wzw);
      }
#pragma unroll
      for (int j = 0; j < 4; j++) {
        int b = B0 + j, p = j >> 1;
        float aq0 = (j & 1) ? a2[0][p].y : a2[0][p].x;
        float aq1 = (j & 1) ? a2[1][p].y : a2[1][p].x;
        float aq2 = (j & 1) ? a2[2][p].y : a2[2][p].x;
        float aq3 = (j & 1) ? a2[3][p].y : a2[3][p].x;
        float ig = sigm(aq0), fg = sigm(aq1);
        float gg = tanh_fast(aq2), og = sigm(aq3);
        float sn = fmaf(fg, syn[b], ig * gg);
        float rst = (mem[b] > thr1) ? thr1 : 0.0f;  // reset uses OLD mem
        float mn = fmaf(og, tanh_fast(sn), -rst);
        syn[b] = sn;
        mem[b] = mn;
        unsigned long long msk = __ballot(mn > thr1);  // wave-uniform
        if (lane == b) myspk = msk;
      }
      __builtin_amdgcn_sched_barrier(0);
    }
    if (lane < NB)
      spk_out[(size_t)t * BB + wb + lane] = myspk;
  }
#pragma unroll
  for (int b = 0; b < NB; b++)
    mem1_out[(size_t)(wb + b) * 64 + lane] = mem[b];
}

__global__ __attribute__((amdgpu_waves_per_eu(4, 4))) __launch_bounds__(1024)
void snn_pass2(
    const float* __restrict__ Wih2, const float* __restrict__ Whh2,
    const float* __restrict__ bih2, const float* __restrict__ bhh2,
    const float* __restrict__ thr2p, const float* __restrict__ Wout,
    const float* __restrict__ bout,
    const unsigned long long* __restrict__ spk_in,
    const float* __restrict__ mem1_in, float* __restrict__ out) {
  __shared__ float4 Pih[64][64];     // 64 KB
  __shared__ float4 Phh[64][64];     // 64 KB
  __shared__ float stM[16][64][NB];  // 32 KB -> 160 KB total
  int tid = threadIdx.x;
  for (int idx = tid; idx < 16384; idx += 1024) {
    int k = idx >> 6, m = idx & 63;
    ((float*)&Pih[m][k & 63])[k >> 6] = Wih2[idx];
    ((float*)&Phh[m][k & 63])[k >> 6] = Whh2[idx];
  }
  __syncthreads();
  int lane = tid & 63, wave = tid >> 6;
  int wb = (blockIdx.x * 16 + wave) * NB;
  float thr2 = thr2p[0];
  float b2q[4];
#pragma unroll
  for (int q = 0; q < 4; q++) b2q[q] = bih2[q * 64 + lane] + bhh2[q * 64 + lane];
  float syn[NB], mem[NB];
  unsigned sb8[NB];  // per-lane spike history of THIS lane's neuron, bit t
#pragma unroll
  for (int b = 0; b < NB; b++) { syn[b] = 0.0f; mem[b] = 0.0f; sb8[b] = 0u; }

  for (int t = 0; t < TT; t++) {
    // spike masks -> SGPR u64 (wave-uniform)
    unsigned long long mk[NB];
#pragma unroll
    for (int b = 0; b < NB; b++) {
      unsigned long long v = spk_in[(size_t)t * BB + wb + b];
      unsigned lo = __builtin_amdgcn_readfirstlane((unsigned)v);
      unsigned hi = __builtin_amdgcn_readfirstlane((unsigned)(v >> 32));
      mk[b] = ((unsigned long long)hi << 32) | (unsigned long long)lo;
    }
#pragma unroll
    for (int b = 0; b < NB; b++) stM[wave][lane][b] = mem[b];
#pragma unroll
    for (int h = 0; h < 2; h++) {
      const int B0 = h * 4;
      pf2 a2[4][2];
#pragma unroll
      for (int q = 0; q < 4; q++) {
#pragma unroll
        for (int p = 0; p < 2; p++) a2[q][p] = (pf2){b2q[q], b2q[q]};
      }
      // dense hh half: packed dual-FMA over batch pairs
#pragma unroll 8
      for (int m = 0; m < 64; m++) {
        float4 wh = Phh[m][lane];
        float4 sa = *(const float4*)&stM[wave][m][B0];
        pf2 s01 = {sa.x, sa.y}, s23 = {sa.z, sa.w};
        pf2 wxy = {wh.x, wh.y}, wzw = {wh.z, wh.w};
        pk_fma_wlo(a2[0][0], s01, wxy);
        pk_fma_whi(a2[1][0], s01, wxy);
        pk_fma_wlo(a2[2][0], s01, wzw);
        pk_fma_whi(a2[3][0], s01, wzw);
        pk_fma_wlo(a2[0][1], s23, wxy);
        pk_fma_whi(a2[1][1], s23, wxy);
        pk_fma_wlo(a2[2][1], s23, wzw);
        pk_fma_whi(a2[3][1], s23, wzw);
      }
      // sparse ih half: 4-deep pipeline; adds land on the pair half of batch j
#pragma unroll
      for (int j = 0; j < 4; j++) {
        int b = B0 + j, p = j >> 1;
        unsigned long long k = mk[b];
        while (__builtin_popcountll(k) >= 4) {
          int m0 = __builtin_ctzll(k); k &= k - 1;
          int m1 = __builtin_ctzll(k); k &= k - 1;
          int m2 = __builtin_ctzll(k); k &= k - 1;
          int m3 = __builtin_ctzll(k); k &= k - 1;
          float4 r0 = Pih[m0][lane];
          float4 r1 = Pih[m1][lane];
          float4 r2 = Pih[m2][lane];
          float4 r3 = Pih[m3][lane];
          if ((j & 1) == 0) {
            a2[0][p].x += r0.x; a2[1][p].x += r0.y; a2[2][p].x += r0.z; a2[3][p].x += r0.w;
            a2[0][p].x += r1.x; a2[1][p].x += r1.y; a2[2][p].x += r1.z; a2[3][p].x += r1.w;
            a2[0][p].x += r2.x; a2[1][p].x += r2.y; a2[2][p].x += r2.z; a2[3][p].x += r2.w;
            a2[0][p].x += r3.x; a2[1][p].x += r3.y; a2[2][p].x += r3.z; a2[3][p].x += r3.w;
          } else {
            a2[0][p].y += r0.x; a2[1][p].y += r0.y; a2[2][p].y += r0.z; a2[3][p].y += r0.w;
            a2[0][p].y += r1.x; a2[1][p].y += r1.y; a2[2][p].y += r1.z; a2[3][p].y += r1.w;
            a2[0][p].y += r2.x; a2[1][p].y += r2.y; a2[2][p].y += r2.z; a2[3][p].y += r2.w;
            a2[0][p].y += r3.x; a2[1][p].y += r3.y; a2[2][p].y += r3.z; a2[3][p].y += r3.w;
          }
        }
        while (k) {
          int m0 = __builtin_ctzll(k); k &= k - 1;
          float4 r0 = Pih[m0][lane];
          if ((j & 1) == 0) {
            a2[0][p].x += r0.x; a2[1][p].x += r0.y; a2[2][p].x += r0.z; a2[3][p].x += r0.w;
          } else {
            a2[0][p].y += r0.x; a2[1][p].y += r0.y; a2[2][p].y += r0.z; a2[3][p].y += r0.w;
          }
        }
        float aq0 = (j & 1) ? a2[0][p].y : a2[0][p].x;
        float aq1 = (j & 1) ? a2[1][p].y : a2[1][p].x;
        float aq2 = (j & 1) ? a2[2][p].y : a2[2][p].x;
        float aq3 = (j & 1) ? a2[3][p].y : a2[3][p].x;
        float ig = sigm(aq0), fg = sigm(aq1);
        float gg = tanh_fast(aq2), og = sigm(aq3);
        float sn = fmaf(fg, syn[b], ig * gg);
        float rst = (mem[b] > thr2) ? thr2 : 0.0f;
        float mn = fmaf(og, tanh_fast(sn), -rst);
        syn[b] = sn;
        mem[b] = mn;
        sb8[b] |= (mn > thr2) ? (1u << t) : 0u;
      }
      __builtin_amdgcn_sched_barrier(0);
    }
  }

  // extra step: input = final mem1 (dense). Readlane form (4% of work).
  float m1[NB];
#pragma unroll
  for (int b = 0; b < NB; b++) m1[b] = mem1_in[(size_t)(wb + b) * 64 + lane];
  float acc[NB][4];
#pragma unroll
  for (int b = 0; b < NB; b++) {
#pragma unroll
    for (int q = 0; q < 4; q++) acc[b][q] = b2q[q];
  }
#pragma unroll 4
  for (int m = 0; m < 64; m++) {
    float4 wi = Pih[m][lane];
    float4 wh = Phh[m][lane];
#pragma unroll
    for (int b = 0; b < NB; b++) {
      float s1 = bcastf(m1[b], m);
      float s2 = bcastf(mem[b], m);
      acc[b][0] = fmaf(s1, wi.x, fmaf(s2, wh.x, acc[b][0]));
      acc[b][1] = fmaf(s1, wi.y, fmaf(s2, wh.y, acc[b][1]));
      acc[b][2] = fmaf(s1, wi.z, fmaf(s2, wh.z, acc[b][2]));
      acc[b][3] = fmaf(s1, wi.w, fmaf(s2, wh.w, acc[b][3]));
    }
  }
  // epilogue: replay p0/p1 accumulation (same fmaf order) from sb8 bits.
  float p0[NB], p1[NB];
#pragma unroll
  for (int b = 0; b < NB; b++) { p0[b] = 0.0f; p1[b] = 0.0f; }
#pragma unroll 4
  for (int t = 0; t < TT; t++) {
    float w0 = Wout[t * 64 + lane];
    float w1 = Wout[1664 + t * 64 + lane];
#pragma unroll
    for (int b = 0; b < NB; b++) {
      float sf = ((sb8[b] >> t) & 1u) ? 1.0f : 0.0f;
      p0[b] = fmaf(sf, w0, p0[b]);
      p1[b] = fmaf(sf, w1, p1[b]);
    }
  }
  float wA0 = Wout[1536 + lane], wA1 = Wout[1664 + 1536 + lane];  // spk2_last
  float wB0 = Wout[1600 + lane], wB1 = Wout[1664 + 1600 + lane];  // mem2 final
  float bo0 = bout[0], bo1 = bout[1];
#pragma unroll
  for (int b = 0; b < NB; b++) {
    float ig = sigm(acc[b][0]), fg = sigm(acc[b][1]);
    float gg = tanh_fast(acc[b][2]), og = sigm(acc[b][3]);
    float sn = fmaf(fg, syn[b], ig * gg);
    float rst = (mem[b] > thr2) ? thr2 : 0.0f;
    float mn = fmaf(og, tanh_fast(sn), -rst);
    float sf = (mn > thr2) ? 1.0f : 0.0f;
    p0[b] = fmaf(sf, wA0, p0[b]);
    p1[b] = fmaf(sf, wA1, p1[b]);
    p0[b] = fmaf(mn, wB0, p0[b]);
    p1[b] = fmaf(mn, wB1, p1[b]);
  }
  // cross-lane reduce; wsum result is uniform, keep own lane's value.
  float vout = 0.0f;
#pragma unroll
  for (int b = 0; b < NB; b++) {
    float r0 = wsum(p0[b]);
    float r1 = wsum(p1[b]);
    if (lane == 2 * b) vout = r0;
    if (lane == 2 * b + 1) vout = r1;
  }
  if (lane < 2 * NB)
    out[(size_t)wb * 2 + lane] = vout + ((lane & 1) ? bo1 : bo0);
}

extern "C" void kernel_launch(void* const* d_in, const int* in_sizes, int n_in,
                              void* d_out, int out_size, void* d_ws, size_t ws_size,
                              hipStream_t stream) {
  const float* x = (const float*)d_in[0];
  const float* Wih1 = (const float*)d_in[1];
  const float* Whh1 = (const float*)d_in[2];
  const float* bih1 = (const float*)d_in[3];
  const float* bhh1 = (const float*)d_in[4];
  const float* thr1 = (const float*)d_in[5];
  const float* Wih2 = (const float*)d_in[6];
  const float* Whh2 = (const float*)d_in[7];
  const float* bih2 = (const float*)d_in[8];
  const float* bhh2 = (const float*)d_in[9];
  const float* thr2 = (const float*)d_in[10];
  const float* Wout = (const float*)d_in[11];
  const float* bout = (const float*)d_in[12];

  unsigned long long* spk = (unsigned long long*)d_ws;
  float* mem1 = (float*)((char*)d_ws + (size_t)TT * BB * 8);

  snn_pass1<<<BB / (8 * NB), 512, 0, stream>>>(x, Wih1, Whh1, bih1, bhh1, thr1,
                                               spk, mem1);
  snn_pass2<<<BB / (16 * NB), 1024, 0, stream>>>(Wih2, Whh2, bih2, bhh2, thr2,
                                                 Wout, bout, spk, mem1,
                                                 (float*)d_out);
}